// Round 1
// baseline (3474.514 us; speedup 1.0000x reference)
//
#include <hip/hip_runtime.h>
#include <math.h>

// ConvLSTM (Seq2VecRNN2D): 2-layer bidirectional, fused implicit-GEMM + cell update, fp32.
// B=8 T=8 CIN=128 HID=64 G=256 H=W=32.

namespace {
constexpr int B_ = 8, T_ = 8, CIN_ = 128, HID_ = 64, G_ = 256;
constexpr int NPOS = 1024;            // 32*32
constexpr int CTOT = 192;             // packed input channels per step (ih:128 + hh:64)
constexpr int KC = 8;                 // channels per K-chunk
constexpr int NCHUNK = CTOT / KC;     // 24
constexpr size_t SLOT = (size_t)B_ * HID_ * NPOS;   // 524288 floats
constexpr size_t PACKW = (size_t)CTOT * 9 * G_;     // 442368 floats
}

struct StepArgs {
  const float* in0; const float* in1; const float* in2;
  int bstr0, bstr1, bstr2;   // batch strides (floats)
  int C0, C1;                // channel counts of group 0/1 (group2 = 192-C0-C1)
  const float* W;            // packed [192][9][256], o' = hc*4+gate
  const float* bias;         // packed [256] = b_ih+b_hh in o' order
  float* cbuf;               // [B][64][1024] cell state (read prev, write new)
  float* hout;               // [B][64][1024] hidden out
};

// Repack weights: Wp[c][tap][o'] with o' = hc*4 + gate; source o = gate*64 + hc.
// c<128 -> w_ih (Csrc=128), else w_hh (Csrc=64). Also bias pack b_ih+b_hh.
__global__ void pack_weights(const float* __restrict__ wih, const float* __restrict__ whh,
                             const float* __restrict__ bih, const float* __restrict__ bhh,
                             float* __restrict__ Wp, float* __restrict__ bp) {
  int idx = blockIdx.x * 256 + threadIdx.x;            // 0 .. 192*9*256-1
  int op = idx & 255;
  int tap = (idx >> 8) % 9;
  int c = idx / (9 * 256);
  int hc = op >> 2, gate = op & 3;
  int o = gate * 64 + hc;
  float v;
  if (c < 128) v = wih[(o * 128 + c) * 9 + tap];
  else         v = whh[(o * 64 + (c - 128)) * 9 + tap];
  Wp[idx] = v;
  if (idx < G_) bp[idx] = bih[o] + bhh[o];
}

// One ConvLSTM step: gates = conv3x3([g0|g1|g2], Wp) + bias; then cell update.
// Block: batch b, 4-row band, 64-gate ntile (16 hidden ch). 256 threads:
//   hcl = tid>>4 (hidden ch in tile), pg = tid&15 -> 8 consecutive x in one row.
__global__ __launch_bounds__(256, 2) void conv_lstm_step(StepArgs A0, StepArgs A1) {
  StepArgs a = (blockIdx.z == 0) ? A0 : A1;
  const int bx = blockIdx.x;
  const int b = bx >> 5;
  const int band = (bx >> 2) & 7;
  const int ntile = bx & 3;
  const int y0 = band * 4;

  const int tid = threadIdx.x;
  const int hcl = tid >> 4;
  const int pg = tid & 15;
  const int r0 = pg >> 2;          // row within band
  const int xb = (pg & 3) * 8;     // x base (8 consecutive)

  __shared__ float As[KC][6][36];  // 8 ch x (4 rows + halo) x (32 + halo, padded)
  __shared__ float Ws[KC][9][64];  // 8 ch x 9 taps x 64 gates

  float acc[8][4];
  {
    const float4 bv = *(const float4*)(a.bias + ntile * 64 + hcl * 4);
    #pragma unroll
    for (int j = 0; j < 8; ++j) { acc[j][0] = bv.x; acc[j][1] = bv.y; acc[j][2] = bv.z; acc[j][3] = bv.w; }
  }

  for (int ch = 0; ch < NCHUNK; ++ch) {
    const int cg = ch * KC;
    const float* src; int bstr, cs;
    if (cg < a.C0) { src = a.in0; bstr = a.bstr0; cs = cg; }
    else if (cg < a.C0 + a.C1) { src = a.in1; bstr = a.bstr1; cs = cg - a.C0; }
    else { src = a.in2; bstr = a.bstr2; cs = cg - a.C0 - a.C1; }
    const float* sbase = src + (size_t)b * bstr + (size_t)cs * NPOS;
    const float* wbase = a.W + (size_t)cg * (9 * 256) + ntile * 64;

    __syncthreads();
    // Stage input chunk with halo + zero pad: 8 x 6 x 34 elements.
    for (int i = tid; i < KC * 6 * 34; i += 256) {
      const int c = i / 204;
      const int rem = i - c * 204;
      const int r = rem / 34;
      const int xx = rem - r * 34 - 1;     // -1 .. 32
      const int gy = y0 - 1 + r;
      float v = 0.f;
      if (gy >= 0 && gy < 32 && xx >= 0 && xx < 32)
        v = sbase[c * NPOS + gy * 32 + xx];
      As[c][r][xx + 1] = v;
    }
    // Stage weight chunk: 8 x 9 x 64.
    for (int i = tid; i < KC * 9 * 64; i += 256) {
      const int c = i / 576;
      const int rem = i - c * 576;
      Ws[c][rem >> 6][rem & 63] = wbase[(c * 9 + (rem >> 6)) * 256 + (rem & 63)];
    }
    __syncthreads();

    for (int c = 0; c < KC; ++c) {
      float av[3][10];
      #pragma unroll
      for (int dy = 0; dy < 3; ++dy)
        #pragma unroll
        for (int xx = 0; xx < 10; ++xx)
          av[dy][xx] = As[c][r0 + dy][xb + xx];
      #pragma unroll
      for (int ky = 0; ky < 3; ++ky)
        #pragma unroll
        for (int kx = 0; kx < 3; ++kx) {
          const float4 w = *(const float4*)(&Ws[c][ky * 3 + kx][0] + hcl * 4);
          #pragma unroll
          for (int j = 0; j < 8; ++j) {
            const float x = av[ky][j + kx];
            acc[j][0] = fmaf(x, w.x, acc[j][0]);
            acc[j][1] = fmaf(x, w.y, acc[j][1]);
            acc[j][2] = fmaf(x, w.z, acc[j][2]);
            acc[j][3] = fmaf(x, w.w, acc[j][3]);
          }
        }
    }
  }

  // Fused LSTM cell update (thread owns i,f,g,o of one hidden channel, 8 positions).
  const int hc = ntile * 16 + hcl;
  const size_t pbase = ((size_t)b * HID_ + hc) * NPOS + (size_t)(y0 + r0) * 32 + xb;
  #pragma unroll
  for (int j = 0; j < 8; ++j) {
    const float ig = 1.f / (1.f + expf(-acc[j][0]));
    const float fg = 1.f / (1.f + expf(-acc[j][1]));
    const float gg = tanhf(acc[j][2]);
    const float og = 1.f / (1.f + expf(-acc[j][3]));
    const float cp = a.cbuf[pbase + j];
    const float cn = fg * cp + ig * gg;
    a.cbuf[pbase + j] = cn;
    a.hout[pbase + j] = og * tanhf(cn);
  }
}

// out[b][o][p] = relu(b_out[o] + sum_{c<128} w_out[o][c] * last[b][c][p])
__global__ void final_conv(const float* __restrict__ h1f_last, const float* __restrict__ h1r_last,
                           const float* __restrict__ wout, const float* __restrict__ bout,
                           float* __restrict__ out) {
  __shared__ float Ws[16 * 128];
  const int oq = blockIdx.y;  // 0..3
  for (int i = threadIdx.x; i < 16 * 128; i += 256)
    Ws[i] = wout[oq * 16 * 128 + i];
  __syncthreads();
  const int gp = blockIdx.x * 256 + threadIdx.x;  // 0..8191
  const int b = gp >> 10, p = gp & 1023;
  float acc[16];
  #pragma unroll
  for (int o = 0; o < 16; ++o) acc[o] = bout[oq * 16 + o];
  for (int c = 0; c < 128; ++c) {
    const float xv = (c < 64) ? h1f_last[((size_t)b * 64 + c) * 1024 + p]
                              : h1r_last[((size_t)b * 64 + (c - 64)) * 1024 + p];
    #pragma unroll
    for (int o = 0; o < 16; ++o) acc[o] = fmaf(xv, Ws[o * 128 + c], acc[o]);
  }
  #pragma unroll
  for (int o = 0; o < 16; ++o) {
    const float v = acc[o];
    out[((size_t)b * 64 + oq * 16 + o) * 1024 + p] = v > 0.f ? v : 0.f;
  }
}

extern "C" void kernel_launch(void* const* d_in, const int* in_sizes, int n_in,
                              void* d_out, int out_size, void* d_ws, size_t ws_size,
                              hipStream_t stream) {
  const float* features = (const float*)d_in[0];
  float* ws = (float*)d_ws;

  // Workspace layout (floats): ~18.5M floats (~74 MB).
  float* Wp = ws;                       // 4 * PACKW
  float* bp = Wp + 4 * PACKW;           // 4 * 256
  float* c0f = bp + 4 * G_;
  float* c0r = c0f + SLOT;
  float* c1f = c0r + SLOT;
  float* c1r = c1f + SLOT;
  float* zbuf = c1r + SLOT;             // zeros (h_prev for layer1-reverse)
  float* hf0 = zbuf + SLOT;             // 9 slots: h_t at slot t+1, slot0 = 0
  float* hr0 = hf0 + 9 * SLOT;          // 9 slots: h_t at slot t,   slot8 = 0
  float* h1f = hr0 + 9 * SLOT;          // 9 slots like hf0
  float* h1r = h1f + 9 * SLOT;          // 1 slot (t = T-1 of layer1 reverse)

  // Zero init: c-states, zbuf, and the zero h-slots.
  hipMemsetAsync(c0f, 0, 5 * SLOT * sizeof(float), stream);       // c0f..c1r + zbuf
  hipMemsetAsync(hf0, 0, SLOT * sizeof(float), stream);           // hf0 slot 0
  hipMemsetAsync(hr0 + 8 * SLOT, 0, SLOT * sizeof(float), stream);// hr0 slot 8
  hipMemsetAsync(h1f, 0, SLOT * sizeof(float), stream);           // h1f slot 0

  // Pack weights for the 4 (layer,dir) combos: d_in[1..4],[5..8],[9..12],[13..16].
  for (int combo = 0; combo < 4; ++combo) {
    const int base = 1 + combo * 4;
    pack_weights<<<dim3((unsigned)(PACKW / 256)), 256, 0, stream>>>(
        (const float*)d_in[base], (const float*)d_in[base + 1],
        (const float*)d_in[base + 2], (const float*)d_in[base + 3],
        Wp + (size_t)combo * PACKW, bp + combo * G_);
  }

  const int FB = T_ * CIN_ * NPOS;   // features batch stride
  const int HB = HID_ * NPOS;        // hidden batch stride

  auto l0f = [&](int t) {
    StepArgs s;
    s.in0 = features + (size_t)t * CIN_ * NPOS; s.bstr0 = FB; s.C0 = 128;
    s.in1 = hf0 + (size_t)t * SLOT; s.bstr1 = HB; s.C1 = 64;
    s.in2 = zbuf; s.bstr2 = HB;
    s.W = Wp + 0 * PACKW; s.bias = bp + 0 * G_;
    s.cbuf = c0f; s.hout = hf0 + (size_t)(t + 1) * SLOT;
    return s;
  };
  auto l0r = [&](int t) {
    StepArgs s;
    s.in0 = features + (size_t)t * CIN_ * NPOS; s.bstr0 = FB; s.C0 = 128;
    s.in1 = hr0 + (size_t)(t + 1) * SLOT; s.bstr1 = HB; s.C1 = 64;
    s.in2 = zbuf; s.bstr2 = HB;
    s.W = Wp + 1 * PACKW; s.bias = bp + 1 * G_;
    s.cbuf = c0r; s.hout = hr0 + (size_t)t * SLOT;
    return s;
  };
  auto l1f = [&](int t) {
    StepArgs s;
    s.in0 = hf0 + (size_t)(t + 1) * SLOT; s.bstr0 = HB; s.C0 = 64;
    s.in1 = hr0 + (size_t)t * SLOT; s.bstr1 = HB; s.C1 = 64;
    s.in2 = h1f + (size_t)t * SLOT; s.bstr2 = HB;
    s.W = Wp + 2 * PACKW; s.bias = bp + 2 * G_;
    s.cbuf = c1f; s.hout = h1f + (size_t)(t + 1) * SLOT;
    return s;
  };
  auto l1r = [&]() {   // single step at t = T-1, zero initial state
    StepArgs s;
    s.in0 = hf0 + (size_t)8 * SLOT; s.bstr0 = HB; s.C0 = 64;
    s.in1 = hr0 + (size_t)7 * SLOT; s.bstr1 = HB; s.C1 = 64;
    s.in2 = zbuf; s.bstr2 = HB;
    s.W = Wp + 3 * PACKW; s.bias = bp + 3 * G_;
    s.cbuf = c1r; s.hout = h1r;
    return s;
  };

  // Layer 0: both directions per launch (z=0 fwd step k, z=1 rev step 7-k).
  for (int k = 0; k < 8; ++k) {
    StepArgs f = l0f(k), r = l0r(7 - k);
    conv_lstm_step<<<dim3(256, 1, 2), 256, 0, stream>>>(f, r);
  }
  // Layer 1: forward chain; the single reverse step rides along at k=0.
  for (int k = 0; k < 8; ++k) {
    StepArgs f = l1f(k);
    if (k == 0) {
      StepArgs r = l1r();
      conv_lstm_step<<<dim3(256, 1, 2), 256, 0, stream>>>(f, r);
    } else {
      conv_lstm_step<<<dim3(256, 1, 1), 256, 0, stream>>>(f, f);
    }
  }

  final_conv<<<dim3(32, 4), 256, 0, stream>>>(
      h1f + (size_t)8 * SLOT, h1r,
      (const float*)d_in[17], (const float*)d_in[18], (float*)d_out);
}

// Round 2
// 3103.136 us; speedup vs baseline: 1.1197x; 1.1197x over previous
//
#include <hip/hip_runtime.h>
#include <math.h>
#include <stdint.h>

// ConvLSTM (Seq2VecRNN2D), MFMA version: fp32-accurate GEMM via 3-term bf16 split
// (Ah*Wh + Ah*Wl + Al*Wh), implicit conv by tap decomposition, fused LSTM cell.
// B=8 T=8 CIN=128 HID=64 G=256 H=W=32.

typedef __attribute__((ext_vector_type(8))) short short8;
typedef __attribute__((ext_vector_type(4))) float float4v;

namespace {
constexpr int NPOS = 1024;
constexpr size_t S = 8ull * 64 * 1024;          // one activation slot [B][64][1024]
constexpr size_t WPC = 442368;                  // u32 per packed weight combo (6*9*2*256*16)
}

__device__ __forceinline__ uint16_t bf16_rne(float x) {
  uint32_t u = __builtin_bit_cast(uint32_t, x);
  return (uint16_t)((u + 0x7FFFu + ((u >> 16) & 1u)) >> 16);
}
__device__ __forceinline__ float bf16_to_f(uint16_t h) {
  uint32_t u = ((uint32_t)h) << 16;
  return __builtin_bit_cast(float, u);
}
__device__ __forceinline__ uint32_t pack_hl(float x) {
  uint16_t hi = bf16_rne(x);
  float r = x - bf16_to_f(hi);
  uint16_t lo = bf16_rne(r);
  return ((uint32_t)hi << 16) | lo;
}

// features fp32 -> packed (hi<<16|lo) u32, same flat layout.
__global__ void pack_features(const float* __restrict__ in, uint32_t* __restrict__ out) {
  int i = blockIdx.x * 256 + threadIdx.x;
  out[i] = pack_hl(in[i]);
}

// Packed weights: per combo, u32 idx = (((cg*9+tap)*2+p)*256 + n)*16 + k2;
// u32 holds k=2k2 (low half) and 2k2+1 (high), plane p=0 -> hi, p=1 -> lo.
// channel c = cg*32+k: c<128 -> w_ih[n][c][tap], else w_hh[n][c-128][tap].
struct WPackArgs {
  const float* wih[4]; const float* whh[4];
  const float* bih[4]; const float* bhh[4];
  uint32_t* wp; float* bp;
};
__global__ void pack_weights_all(WPackArgs A) {
  const int combo = blockIdx.y;
  const int idx = blockIdx.x * 256 + threadIdx.x;   // < 442368
  const float* wih = A.wih[combo];
  const float* whh = A.whh[combo];
  const int k2 = idx & 15;
  const int n = (idx >> 4) & 255;
  const int p = (idx >> 12) & 1;
  const int ct = idx >> 13;            // 0..53
  const int tap = ct % 9, cg = ct / 9;
  uint32_t out = 0;
  #pragma unroll
  for (int e = 0; e < 2; ++e) {
    const int c = cg * 32 + 2 * k2 + e;
    const float w = (c < 128) ? wih[(n * 128 + c) * 9 + tap]
                              : whh[(n * 64 + (c - 128)) * 9 + tap];
    const uint16_t hi = bf16_rne(w);
    const uint16_t v = (p == 0) ? hi : bf16_rne(w - bf16_to_f(hi));
    out |= ((uint32_t)v) << (16 * e);
  }
  A.wp[(size_t)combo * WPC + idx] = out;
  if (idx < 256) A.bp[combo * 256 + idx] = A.bih[combo][idx] + A.bhh[combo][idx];
}

struct StepArgs {
  const uint32_t *in0, *in1, *in2;  // packed activations [b][C][1024]
  int bs0, bs1, bs2;                // batch strides (u32 elements)
  int cg0, cg01;                    // 32-ch group boundaries: <cg0 -> in0, <cg01 -> in1, else in2
  const uint32_t* W;                // packed weights (combo base, u32 view)
  const float* bias;                // [256] (gate*64+hc order)
  float* cbuf;                      // [b][64][1024] fp32 cell state
  uint32_t* hout;                   // [b][64][1024] packed hidden out
};

// Block: batch b (bx>>5), band of 2 rows ((bx>>1)&15), hc-tile of 32 (bx&1).
// 256 threads = 4 waves; wave w: row w&1, hc-subgroup (w>>1)*16. Wave computes
// 2 m-frags (x-halves) x [4 gates x 16 hc] with 3-term split MFMA.
__global__ __launch_bounds__(256, 2) void conv_lstm_step(StepArgs A0, StepArgs A1) {
  StepArgs a = (blockIdx.z == 0) ? A0 : A1;
  const int bx = blockIdx.x;
  const int b = bx >> 5;
  const int band = (bx >> 1) & 15;
  const int ntile = bx & 1;
  const int y0 = band * 2;

  const int tid = threadIdx.x;
  const int lane = tid & 63;
  const int w = tid >> 6;
  const int w1 = w & 1;          // row within the 2-row tile
  const int hcg = w >> 1;        // 16-hc subgroup
  const int m15 = lane & 15;
  const int kg = lane >> 4;

  __shared__ union {
    struct { uint16_t A[4 * 34 * 72]; uint16_t W[2][2 * 4 * 32 * 40]; } s;
    struct { float c[32 * 68]; uint32_t h[32 * 68]; } e;
  } L;

  float4v acc[2][4];
  {
    const float4v z = {0.f, 0.f, 0.f, 0.f};
    #pragma unroll
    for (int xh = 0; xh < 2; ++xh)
      #pragma unroll
      for (int g = 0; g < 4; ++g) acc[xh][g] = z;
  }

  const int laneA = m15 * 72 + kg * 8;   // u16 units
  const int laneW = m15 * 40 + kg * 8;

  for (int cg = 0; cg < 6; ++cg) {
    const uint32_t* src; int bs, cl;
    if (cg < a.cg0)       { src = a.in0; bs = a.bs0; cl = cg; }
    else if (cg < a.cg01) { src = a.in1; bs = a.bs1; cl = cg - a.cg0; }
    else                  { src = a.in2; bs = a.bs2; cl = cg - a.cg01; }
    const uint32_t* sb = src + (size_t)b * bs + (size_t)cl * 32 * NPOS;
    const uint32_t* wb = a.W + (size_t)cg * 9 * 8192;

    for (int tp = 0; tp < 5; ++tp) {
      __syncthreads();
      if (tp == 0) {
        // Stage A (hi/lo planes): 16 ch-pairs x 4 rows x 34 x.
        uint32_t* au = (uint32_t*)L.s.A;
        for (int q = tid; q < 2176; q += 256) {
          const int c0g = q / 136;
          const int rem = q - c0g * 136;
          const int r = rem / 34, xx = rem - r * 34;
          const int y = y0 - 1 + r, x = xx - 1;
          uint32_t u0 = 0, u1 = 0;
          if ((unsigned)y < 32u && (unsigned)x < 32u) {
            const int off = 2 * c0g * NPOS + y * 32 + x;
            u0 = sb[off]; u1 = sb[off + NPOS];
          }
          const int pos = r * 34 + xx;
          au[pos * 36 + c0g] = (u1 & 0xFFFF0000u) | (u0 >> 16);       // hi plane
          au[pos * 36 + 16 + c0g] = (u1 << 16) | (u0 & 0xFFFFu);      // lo plane
        }
      }
      const int tap0 = tp * 2;
      const int ntaps = (tap0 + 1 < 9) ? 2 : 1;
      for (int tt = 0; tt < ntaps; ++tt) {
        const uint32_t* wt = wb + (size_t)(tap0 + tt) * 8192;
        uint32_t* wu = (uint32_t*)L.s.W[tt];
        for (int q = tid; q < 4096; q += 256) {
          const int k2 = q & 15;
          const int nl = (q >> 4) & 31;
          const int g = (q >> 9) & 3;
          const int p = q >> 11;
          const uint32_t v = wt[p * 4096 + (g * 64 + ntile * 32 + nl) * 16 + k2];
          wu[((p * 4 + g) * 32 + nl) * 20 + k2] = v;
        }
      }
      __syncthreads();
      for (int tt = 0; tt < ntaps; ++tt) {
        const int tap = tap0 + tt;
        const int ky = tap / 3, kx = tap - ky * 3;
        const uint16_t* au = L.s.A;
        const uint16_t* wuu = L.s.W[tt];
        short8 af[2][2];
        #pragma unroll
        for (int xh = 0; xh < 2; ++xh) {
          const int base = ((w1 + ky) * 34 + xh * 16 + kx) * 72;
          af[xh][0] = *(const short8*)&au[base + laneA];
          af[xh][1] = *(const short8*)&au[base + 32 + laneA];
        }
        short8 wf[4][2];
        #pragma unroll
        for (int g = 0; g < 4; ++g) {
          wf[g][0] = *(const short8*)&wuu[((0 * 4 + g) * 32 + hcg * 16) * 40 + laneW];
          wf[g][1] = *(const short8*)&wuu[((1 * 4 + g) * 32 + hcg * 16) * 40 + laneW];
        }
        #pragma unroll
        for (int xh = 0; xh < 2; ++xh)
          #pragma unroll
          for (int g = 0; g < 4; ++g) {
            acc[xh][g] = __builtin_amdgcn_mfma_f32_16x16x32_bf16(af[xh][0], wf[g][0], acc[xh][g], 0, 0, 0);
            acc[xh][g] = __builtin_amdgcn_mfma_f32_16x16x32_bf16(af[xh][0], wf[g][1], acc[xh][g], 0, 0, 0);
            acc[xh][g] = __builtin_amdgcn_mfma_f32_16x16x32_bf16(af[xh][1], wf[g][0], acc[xh][g], 0, 0, 0);
          }
      }
    }
  }

  // ---- Fused LSTM cell epilogue (LDS transpose for coalesced c/h I/O) ----
  __syncthreads();
  const int hcs = ntile * 32;
  {
    const int hc2 = tid >> 3, chunk = tid & 7;
    const float* gsrc = a.cbuf + ((size_t)(b * 64 + hcs + hc2)) * NPOS + y0 * 32 + chunk * 8;
    float* dst = &L.e.c[hc2 * 68 + chunk * 8];
    #pragma unroll
    for (int j = 0; j < 8; ++j) dst[j] = gsrc[j];
  }
  __syncthreads();
  const int hcl = hcg * 16 + m15;       // 0..31
  const int hc = hcs + hcl;
  float bia[4];
  #pragma unroll
  for (int g = 0; g < 4; ++g) bia[g] = a.bias[g * 64 + hc];
  #pragma unroll
  for (int xh = 0; xh < 2; ++xh) {
    #pragma unroll
    for (int r = 0; r < 4; ++r) {
      const int pos = w1 * 32 + xh * 16 + kg * 4 + r;
      const float pi = acc[xh][0][r] + bia[0];
      const float pf = acc[xh][1][r] + bia[1];
      const float pg = acc[xh][2][r] + bia[2];
      const float po = acc[xh][3][r] + bia[3];
      const float ig = 1.f / (1.f + expf(-pi));
      const float fg = 1.f / (1.f + expf(-pf));
      const float gg = tanhf(pg);
      const float og = 1.f / (1.f + expf(-po));
      const float cp = L.e.c[hcl * 68 + pos];
      const float cn = fg * cp + ig * gg;
      L.e.c[hcl * 68 + pos] = cn;
      L.e.h[hcl * 68 + pos] = pack_hl(og * tanhf(cn));
    }
  }
  __syncthreads();
  {
    const int hc2 = tid >> 3, chunk = tid & 7;
    const size_t gb = ((size_t)(b * 64 + hcs + hc2)) * NPOS + y0 * 32 + chunk * 8;
    #pragma unroll
    for (int j = 0; j < 8; ++j) a.cbuf[gb + j] = L.e.c[hc2 * 68 + chunk * 8 + j];
    #pragma unroll
    for (int j = 0; j < 8; ++j) a.hout[gb + j] = L.e.h[hc2 * 68 + chunk * 8 + j];
  }
}

// out[b][o][p] = relu(b_out[o] + sum_c w_out[o][c] * last[b][c][p]); last is packed hi/lo.
__global__ void final_conv(const uint32_t* __restrict__ h1f_last, const uint32_t* __restrict__ h1r_,
                           const float* __restrict__ wout, const float* __restrict__ bout,
                           float* __restrict__ out) {
  __shared__ float Ws[16 * 128];
  const int oq = blockIdx.y;
  for (int i = threadIdx.x; i < 16 * 128; i += 256) Ws[i] = wout[oq * 16 * 128 + i];
  __syncthreads();
  const int gp = blockIdx.x * 256 + threadIdx.x;
  const int b = gp >> 10, p = gp & 1023;
  float acc[16];
  #pragma unroll
  for (int o = 0; o < 16; ++o) acc[o] = bout[oq * 16 + o];
  for (int c = 0; c < 128; ++c) {
    const uint32_t u = (c < 64) ? h1f_last[((size_t)b * 64 + c) * NPOS + p]
                                : h1r_[((size_t)b * 64 + (c - 64)) * NPOS + p];
    const float xv = __builtin_bit_cast(float, u & 0xFFFF0000u) +
                     __builtin_bit_cast(float, u << 16);
    #pragma unroll
    for (int o = 0; o < 16; ++o) acc[o] = fmaf(xv, Ws[o * 128 + c], acc[o]);
  }
  #pragma unroll
  for (int o = 0; o < 16; ++o) {
    const float v = acc[o];
    out[((size_t)b * 64 + oq * 16 + o) * NPOS + p] = v > 0.f ? v : 0.f;
  }
}

extern "C" void kernel_launch(void* const* d_in, const int* in_sizes, int n_in,
                              void* d_out, int out_size, void* d_ws, size_t ws_size,
                              hipStream_t stream) {
  uint32_t* ws = (uint32_t*)d_ws;

  uint32_t* featP = ws;                       // 8388608 u32
  uint32_t* WP = featP + 8388608;             // 4 * 442368
  float* bp = (float*)(WP + 4 * WPC);         // 1024 floats
  float* c0f = bp + 1024;
  float* c0r = c0f + S;
  float* c1f = c0r + S;
  float* c1r = c1f + S;
  uint32_t* zbuf = (uint32_t*)(c1r + S);      // packed zeros
  uint32_t* hf0 = zbuf + S;                   // 9 slots (h_t at slot t+1)
  uint32_t* hr0 = hf0 + 9 * S;                // 9 slots (h_t at slot t)
  uint32_t* h1f = hr0 + 9 * S;                // 9 slots
  uint32_t* h1r = h1f + 9 * S;                // 1 slot

  // Zero init: c-states + zbuf (contiguous), and the zero h slots.
  hipMemsetAsync(c0f, 0, 5 * S * sizeof(float), stream);
  hipMemsetAsync(hf0, 0, S * sizeof(uint32_t), stream);
  hipMemsetAsync(hr0 + 8 * S, 0, S * sizeof(uint32_t), stream);
  hipMemsetAsync(h1f, 0, S * sizeof(uint32_t), stream);

  pack_features<<<dim3(32768), 256, 0, stream>>>((const float*)d_in[0], featP);

  WPackArgs wa;
  for (int combo = 0; combo < 4; ++combo) {
    const int base = 1 + combo * 4;
    wa.wih[combo] = (const float*)d_in[base];
    wa.whh[combo] = (const float*)d_in[base + 1];
    wa.bih[combo] = (const float*)d_in[base + 2];
    wa.bhh[combo] = (const float*)d_in[base + 3];
  }
  wa.wp = WP; wa.bp = bp;
  pack_weights_all<<<dim3(1728, 4), 256, 0, stream>>>(wa);

  const int FB = 8 * 128 * 1024;   // features batch stride (u32)
  const int HB = 64 * 1024;        // hidden batch stride

  auto l0f = [&](int t) {
    StepArgs s;
    s.in0 = featP + (size_t)t * 128 * 1024; s.bs0 = FB;
    s.in1 = hf0 + (size_t)t * S; s.bs1 = HB;
    s.in2 = zbuf; s.bs2 = HB;
    s.cg0 = 4; s.cg01 = 6;
    s.W = WP + 0 * WPC; s.bias = bp + 0 * 256;
    s.cbuf = c0f; s.hout = hf0 + (size_t)(t + 1) * S;
    return s;
  };
  auto l0r = [&](int t) {
    StepArgs s;
    s.in0 = featP + (size_t)t * 128 * 1024; s.bs0 = FB;
    s.in1 = hr0 + (size_t)(t + 1) * S; s.bs1 = HB;
    s.in2 = zbuf; s.bs2 = HB;
    s.cg0 = 4; s.cg01 = 6;
    s.W = WP + 1 * WPC; s.bias = bp + 1 * 256;
    s.cbuf = c0r; s.hout = hr0 + (size_t)t * S;
    return s;
  };
  auto l1f = [&](int t) {
    StepArgs s;
    s.in0 = hf0 + (size_t)(t + 1) * S; s.bs0 = HB;
    s.in1 = hr0 + (size_t)t * S; s.bs1 = HB;
    s.in2 = h1f + (size_t)t * S; s.bs2 = HB;
    s.cg0 = 2; s.cg01 = 4;
    s.W = WP + 2 * WPC; s.bias = bp + 2 * 256;
    s.cbuf = c1f; s.hout = h1f + (size_t)(t + 1) * S;
    return s;
  };
  auto l1r = [&]() {
    StepArgs s;
    s.in0 = hf0 + (size_t)8 * S; s.bs0 = HB;
    s.in1 = hr0 + (size_t)7 * S; s.bs1 = HB;
    s.in2 = zbuf; s.bs2 = HB;
    s.cg0 = 2; s.cg01 = 4;
    s.W = WP + 3 * WPC; s.bias = bp + 3 * 256;
    s.cbuf = c1r; s.hout = h1r;
    return s;
  };

  for (int k = 0; k < 8; ++k) {
    StepArgs f = l0f(k), r = l0r(7 - k);
    conv_lstm_step<<<dim3(256, 1, 2), 256, 0, stream>>>(f, r);
  }
  for (int k = 0; k < 8; ++k) {
    StepArgs f = l1f(k);
    if (k == 0) {
      StepArgs r = l1r();
      conv_lstm_step<<<dim3(256, 1, 2), 256, 0, stream>>>(f, r);
    } else {
      conv_lstm_step<<<dim3(256, 1, 1), 256, 0, stream>>>(f, f);
    }
  }

  final_conv<<<dim3(32, 4), 256, 0, stream>>>(
      h1f + (size_t)8 * S, h1r,
      (const float*)d_in[17], (const float*)d_in[18], (float*)d_out);
}

// Round 4
// 992.201 us; speedup vs baseline: 3.5018x; 3.1275x over previous
//
#include <hip/hip_runtime.h>
#include <math.h>
#include <stdint.h>

// ConvLSTM (Seq2VecRNN2D) round 4: MFMA 3-term bf16-split GEMM with
// global_load_lds staging from pre-swizzled activation/weight images.
// B=8 T=8 CIN=128 HID=64 G=256 H=W=32.
//
// Fixes vs round 3: pack_features grid 11560 -> 9248 (OOB reads caused the
// page-fault abort); h1fi 8 slots -> 2-slot ping-pong (ws ~105 MB, under the
// round-2-proven ~110 MB).
//
// Activation image per (slot,b,cg32): [34 y'][34 px][8 blk of 16B], blk = pl*4+kg
// stored at blk^(px&7); ch = cg*32+kg*8+j, pl0=hi bf16, pl1=lo bf16. Borders zero.
// Weight image per (combo,cg,tap,nt): [pl][4 g][16 hcp][8 b8 of 16B], b8 = kg+4*(hc&1)
// stored at b8^(hcp&7); hcp = hc_local>>1.

typedef __attribute__((ext_vector_type(8))) short short8;
typedef __attribute__((ext_vector_type(4))) float float4v;

namespace {
constexpr int IMG = 34 * 34 * 64;            // u16 per (slot,b,cg) image
constexpr size_t SLOTI = 16ull * IMG;        // u16 per h slot (8 b x 2 cg)
constexpr int ROWB = 34 * 128;               // bytes per image row (4352)
}

__device__ __forceinline__ uint16_t bf16_rne(float x) {
  uint32_t u = __builtin_bit_cast(uint32_t, x);
  return (uint16_t)((u + 0x7FFFu + ((u >> 16) & 1u)) >> 16);
}
__device__ __forceinline__ float bf16_to_f(uint16_t h) {
  uint32_t u = ((uint32_t)h) << 16;
  return __builtin_bit_cast(float, u);
}

__device__ __forceinline__ void gl_lds16(const void* g, void* l) {
  __builtin_amdgcn_global_load_lds(
      (const __attribute__((address_space(1))) void*)g,
      (__attribute__((address_space(3))) void*)l, 16, 0, 0);
}

// ---- feature pack: fp32 [B][T][128][32][32] -> swizzled images [t][b][4cg] ----
__global__ void pack_features(const float* __restrict__ f, uint16_t* __restrict__ out) {
  const size_t i = (size_t)blockIdx.x * 256 + threadIdx.x;  // 16B-block index, < 2367488
  const int blk_s = (int)(i & 7);
  size_t pp = i >> 3;
  const int px = (int)(pp % 34); pp /= 34;
  const int yy = (int)(pp % 34); pp /= 34;
  const int cg = (int)(pp & 3);
  const int bt = (int)(pp >> 2);
  const int b = bt & 7, t = bt >> 3;
  const int blk = blk_s ^ (px & 7);
  const int pl = blk >> 2, kg = blk & 3;
  short8 sv;
  if (px == 0 || px == 33 || yy == 0 || yy == 33) {
    #pragma unroll
    for (int j = 0; j < 8; ++j) sv[j] = 0;
  } else {
    const int x = px - 1, y = yy - 1;
    #pragma unroll
    for (int j = 0; j < 8; ++j) {
      const int ch = cg * 32 + kg * 8 + j;
      const float fv = f[(((size_t)b * 8 + t) * 128 + ch) * 1024 + y * 32 + x];
      const uint16_t hi = bf16_rne(fv);
      sv[j] = (short)(pl ? bf16_rne(fv - bf16_to_f(hi)) : hi);
    }
  }
  *(short8*)(out + i * 8) = sv;
}

// ---- weight pack into swizzled images: per combo [cg][tap][nt][4096 u32] ----
struct WPackArgs {
  const float* wih[4]; const float* whh[4];
  const float* bih[4]; const float* bhh[4];
  uint32_t* wp; float* bp;
};
__global__ void pack_weights(WPackArgs A) {
  const int combo = blockIdx.y;
  const int idx = blockIdx.x * 256 + threadIdx.x;  // < 442368
  const int q = idx & 4095;
  const int rest = idx >> 12;
  const int nt = rest & 1;
  const int ct = rest >> 1;          // cg*9+tap
  const int tap = ct % 9, cg = ct / 9;
  const int w2 = q & 3;
  const int b8s = (q >> 2) & 7;
  const int hcp = (q >> 5) & 15;
  const int g = (q >> 9) & 3;
  const int pl = (q >> 11) & 1;
  const int b8 = b8s ^ (hcp & 7);
  const int kg = b8 & 3;
  const int hcl = hcp * 2 + (b8 >> 2);
  const int n = g * 64 + nt * 32 + hcl;
  const float* wih = A.wih[combo];
  const float* whh = A.whh[combo];
  uint32_t out = 0;
  #pragma unroll
  for (int e = 0; e < 2; ++e) {
    const int ch = cg * 32 + kg * 8 + w2 * 2 + e;
    const float wv = (ch < 128) ? wih[((size_t)n * 128 + ch) * 9 + tap]
                                : whh[((size_t)n * 64 + (ch - 128)) * 9 + tap];
    const uint16_t hi = bf16_rne(wv);
    const uint16_t v = pl ? bf16_rne(wv - bf16_to_f(hi)) : hi;
    out |= ((uint32_t)v) << (16 * e);
  }
  A.wp[(size_t)combo * 442368 + idx] = out;
  if (idx < 256) A.bp[combo * 256 + idx] = A.bih[combo][idx] + A.bhh[combo][idx];
}

struct StepArgs {
  const uint16_t* in0; const uint16_t* in1; const uint16_t* in2;  // images
  int nc0, nc1, nc2;         // cg counts per tensor
  const uint32_t* W;         // combo base: [cg][tap][nt][4096 u32]
  const float* bias;         // [256], n = gate*64+hc
  float* cbuf;               // plain fp32 [b][64][1024]
  uint16_t* himg;            // nullable: [b][2 cg][IMG]
  float* hf32;               // nullable: plain [b][64][1024]
};

template <int MROWS>
__global__ __launch_bounds__(256, 2) void conv_lstm_step(StepArgs A0, StepArgs A1) {
  const StepArgs a = (blockIdx.z == 0) ? A0 : A1;
  constexpr int NBANDS = 32 / MROWS;
  constexpr int NXH = (MROWS == 2) ? 2 : 1;
  constexpr int ASZ = (MROWS == 2) ? 17408 : 13312;   // staged A bytes (1KB mult)
  constexpr int NSTG = ASZ / 1024;
  const int bx = blockIdx.x;
  const int nt = bx & 1;
  const int band = (bx >> 1) & (NBANDS - 1);
  const int b = bx >> (MROWS == 2 ? 5 : 6);
  const int y0 = band * MROWS;        // interior y start == staged y' start
  const int tid = threadIdx.x;
  const int lane = tid & 63;
  const int w = tid >> 6;
  const int m15 = lane & 15;
  const int kg = lane >> 4;
  const int w1 = (MROWS == 2) ? (w & 1) : 0;
  const int xh0 = (MROWS == 2) ? 0 : (w & 1);
  const int hcg = w >> 1;

  __shared__ char Asm[ASZ];
  __shared__ char Wsm[2 * 16384];

  // fragment read offsets (bytes), conflict-free via baked swizzle
  int offA[NXH][3][2];
  #pragma unroll
  for (int xi = 0; xi < NXH; ++xi)
    #pragma unroll
    for (int kx = 0; kx < 3; ++kx)
      #pragma unroll
      for (int pl = 0; pl < 2; ++pl) {
        const int px = (xh0 + xi) * 16 + kx + m15;
        const int sw = (pl * 4 + kg) ^ (px & 7);
        offA[xi][kx][pl] = w1 * ROWB + px * 128 + sw * 16;
      }
  int offW[2][4];
  {
    const int hcp = hcg * 8 + (m15 >> 1);
    const int b8 = kg + 4 * (m15 & 1);
    #pragma unroll
    for (int pl = 0; pl < 2; ++pl)
      #pragma unroll
      for (int g = 0; g < 4; ++g)
        offW[pl][g] = (((pl * 4 + g) * 16 + hcp) * 8 + (b8 ^ (hcp & 7))) * 16;
  }

  const int ncg = a.nc0 + a.nc1 + a.nc2;
  auto abase = [&](int cg) -> const char* {
    const uint16_t* t;
    if (cg < a.nc0) t = a.in0 + ((size_t)b * a.nc0 + cg) * IMG;
    else if (cg < a.nc0 + a.nc1) t = a.in1 + ((size_t)b * a.nc1 + (cg - a.nc0)) * IMG;
    else t = a.in2 + ((size_t)b * a.nc2 + (cg - a.nc0 - a.nc1)) * IMG;
    return (const char*)t + (size_t)y0 * ROWB;
  };
  auto stageA = [&](const char* g) {
    for (int i = w; i < NSTG; i += 4)
      gl_lds16(g + (size_t)i * 1024 + lane * 16, Asm + i * 1024);
  };
  auto stageW = [&](int cg, int tap, int wbuf) {
    const char* g = (const char*)(a.W + ((size_t)((cg * 9 + tap) * 2 + nt) << 12));
    for (int i = w; i < 16; i += 4)
      gl_lds16(g + (size_t)i * 1024 + lane * 16, Wsm + wbuf * 16384 + i * 1024);
  };

  float4v acc[NXH][4];
  #pragma unroll
  for (int xi = 0; xi < NXH; ++xi)
    #pragma unroll
    for (int g = 0; g < 4; ++g) acc[xi][g] = (float4v){0.f, 0.f, 0.f, 0.f};

  stageA(abase(0));
  stageW(0, 0, 0);
  for (int cg = 0; cg < ncg; ++cg) {
    #pragma unroll
    for (int tap = 0; tap < 9; ++tap) {
      __syncthreads();   // staged data for (cg,tap) landed; prev compute done
      const int wb = (cg + tap) & 1;
      if (tap < 8) stageW(cg, tap + 1, wb ^ 1);
      else if (cg + 1 < ncg) stageW(cg + 1, 0, wb ^ 1);
      const int ky = tap / 3, kx = tap % 3;
      short8 af[NXH][2];
      #pragma unroll
      for (int xi = 0; xi < NXH; ++xi)
        #pragma unroll
        for (int pl = 0; pl < 2; ++pl)
          af[xi][pl] = *(const short8*)(Asm + ky * ROWB + offA[xi][kx][pl]);
      const char* Wb = Wsm + wb * 16384;
      short8 wfr[2][4];
      #pragma unroll
      for (int pl = 0; pl < 2; ++pl)
        #pragma unroll
        for (int g = 0; g < 4; ++g)
          wfr[pl][g] = *(const short8*)(Wb + offW[pl][g]);
      #pragma unroll
      for (int xi = 0; xi < NXH; ++xi)
        #pragma unroll
        for (int g = 0; g < 4; ++g) {
          acc[xi][g] = __builtin_amdgcn_mfma_f32_16x16x32_bf16(af[xi][0], wfr[0][g], acc[xi][g], 0, 0, 0);
          acc[xi][g] = __builtin_amdgcn_mfma_f32_16x16x32_bf16(af[xi][0], wfr[1][g], acc[xi][g], 0, 0, 0);
          acc[xi][g] = __builtin_amdgcn_mfma_f32_16x16x32_bf16(af[xi][1], wfr[0][g], acc[xi][g], 0, 0, 0);
        }
    }
    if (cg + 1 < ncg) {    // A buffer free only after all waves did tap 8
      __syncthreads();
      stageA(abase(cg + 1));
    }
  }

  // ---- fused LSTM cell epilogue ----
  const int hcl = hcg * 16 + m15;
  const int hc = nt * 32 + hcl;
  const int y = y0 + w1;
  float bi[4];
  #pragma unroll
  for (int g = 0; g < 4; ++g) bi[g] = a.bias[g * 64 + hc];
  float* crow = a.cbuf + ((size_t)(b * 64 + hc)) * 1024 + y * 32;
  float* hrow = a.hf32 ? a.hf32 + ((size_t)(b * 64 + hc)) * 1024 + y * 32 : nullptr;
  uint16_t* hb = a.himg ? a.himg + ((size_t)(b * 2 + nt)) * IMG : nullptr;
  const int kgb = hcl >> 3, jj = hcl & 7;
  #pragma unroll
  for (int xi = 0; xi < NXH; ++xi) {
    const int x0 = (xh0 + xi) * 16 + kg * 4;
    float4v cv = *(float4v*)(crow + x0);
    float4v cn, hn;
    #pragma unroll
    for (int r = 0; r < 4; ++r) {
      const float ig = 1.f / (1.f + expf(-(acc[xi][0][r] + bi[0])));
      const float fg = 1.f / (1.f + expf(-(acc[xi][1][r] + bi[1])));
      const float gg = tanhf(acc[xi][2][r] + bi[2]);
      const float og = 1.f / (1.f + expf(-(acc[xi][3][r] + bi[3])));
      const float c2 = fg * cv[r] + ig * gg;
      cn[r] = c2;
      hn[r] = og * tanhf(c2);
    }
    *(float4v*)(crow + x0) = cn;
    if (hrow) *(float4v*)(hrow + x0) = hn;
    if (hb) {
      #pragma unroll
      for (int r = 0; r < 4; ++r) {
        const int px = x0 + r + 1;
        const int sw = px & 7;
        const uint16_t hi = bf16_rne(hn[r]);
        const uint16_t lo = bf16_rne(hn[r] - bf16_to_f(hi));
        const size_t p16 = ((size_t)(y + 1) * 34 + px) * 64;
        hb[p16 + (size_t)(kgb ^ sw) * 8 + jj] = hi;
        hb[p16 + (size_t)((4 + kgb) ^ sw) * 8 + jj] = lo;
      }
    }
  }
  if (hb) {   // keep image borders zero (ws is re-poisoned every call)
    if (tid < MROWS * 128) {
      const int rr = tid >> 7;
      const int hlf = (tid >> 6) & 1;
      const int jx = tid & 63;
      hb[((size_t)(y0 + 1 + rr) * 34 + hlf * 33) * 64 + jx] = 0;
    }
    if (band == 0) for (int i = tid; i < 2176; i += 256) hb[i] = 0;
    if (band == NBANDS - 1) for (int i = tid; i < 2176; i += 256) hb[(size_t)33 * 2176 + i] = 0;
  }
}

// out[b][o][p] = relu(b_out[o] + sum_c w_out[o][c] * last[b][c][p])  (fp32 inputs)
__global__ void final_conv(const float* __restrict__ h1f_last, const float* __restrict__ h1r_last,
                           const float* __restrict__ wout, const float* __restrict__ bout,
                           float* __restrict__ out) {
  __shared__ float Ws[16 * 128];
  const int oq = blockIdx.y;
  for (int i = threadIdx.x; i < 16 * 128; i += 256) Ws[i] = wout[oq * 16 * 128 + i];
  __syncthreads();
  const int gp = blockIdx.x * 256 + threadIdx.x;
  const int b = gp >> 10, p = gp & 1023;
  float acc[16];
  #pragma unroll
  for (int o = 0; o < 16; ++o) acc[o] = bout[oq * 16 + o];
  for (int c = 0; c < 128; ++c) {
    const float xv = (c < 64) ? h1f_last[((size_t)b * 64 + c) * 1024 + p]
                              : h1r_last[((size_t)b * 64 + (c - 64)) * 1024 + p];
    #pragma unroll
    for (int o = 0; o < 16; ++o) acc[o] = fmaf(xv, Ws[o * 128 + c], acc[o]);
  }
  #pragma unroll
  for (int o = 0; o < 16; ++o) {
    const float v = acc[o];
    out[((size_t)b * 64 + oq * 16 + o) * 1024 + p] = v > 0.f ? v : 0.f;
  }
}

extern "C" void kernel_launch(void* const* d_in, const int* in_sizes, int n_in,
                              void* d_out, int out_size, void* d_ws, size_t ws_size,
                              hipStream_t stream) {
  char* p = (char*)d_ws;
  uint16_t* featImg = (uint16_t*)p; p += (size_t)8 * 8 * 4 * IMG * 2;     // 37.9 MB
  uint32_t* WP = (uint32_t*)p;      p += (size_t)4 * 442368 * 4;          // 7.1 MB
  float* bp = (float*)p;            p += 4096;
  uint16_t* hf0i = (uint16_t*)p;    p += (size_t)9 * SLOTI * 2;           // 21.3 MB
  uint16_t* hr0i = (uint16_t*)p;    p += (size_t)9 * SLOTI * 2;           // 21.3 MB
  uint16_t* h1fi = (uint16_t*)p;    p += (size_t)2 * SLOTI * 2;           // 4.7 MB (ping-pong)
  float* c0f = (float*)p;           p += (size_t)4 * 2097152;             // c0f,c0r,c1f,c1r
  float* c0r = c0f + 524288;
  float* c1f = c0r + 524288;
  float* c1r = c1f + 524288;
  float* h1f8 = (float*)p;          p += 2097152;                         // plain f32
  float* h1r8 = (float*)p;          p += 2097152;

  hipMemsetAsync(c0f, 0, (size_t)4 * 2097152, stream);
  hipMemsetAsync(hf0i, 0, (size_t)SLOTI * 2, stream);                     // hf0 slot 0
  hipMemsetAsync(hr0i + (size_t)8 * SLOTI, 0, (size_t)SLOTI * 2, stream); // hr0 slot 8
  hipMemsetAsync(h1fi, 0, (size_t)SLOTI * 2, stream);                     // h1f parity-0 slot

  pack_features<<<dim3(9248), 256, 0, stream>>>((const float*)d_in[0], featImg);

  WPackArgs wa;
  for (int combo = 0; combo < 4; ++combo) {
    const int base = 1 + combo * 4;
    wa.wih[combo] = (const float*)d_in[base];
    wa.whh[combo] = (const float*)d_in[base + 1];
    wa.bih[combo] = (const float*)d_in[base + 2];
    wa.bhh[combo] = (const float*)d_in[base + 3];
  }
  wa.wp = WP; wa.bp = bp;
  pack_weights<<<dim3(1728, 4), 256, 0, stream>>>(wa);

  auto mk = [&](const uint16_t* i0, int n0, const uint16_t* i1, int n1,
                const uint16_t* i2, int n2, int combo, float* cb,
                uint16_t* himg, float* hf32) {
    StepArgs s;
    s.in0 = i0; s.in1 = i1; s.in2 = i2;
    s.nc0 = n0; s.nc1 = n1; s.nc2 = n2;
    s.W = WP + (size_t)combo * 442368; s.bias = bp + combo * 256;
    s.cbuf = cb; s.himg = himg; s.hf32 = hf32;
    return s;
  };

  // Layer 0: 8 pair launches (fwd step k, rev step 7-k)
  for (int k = 0; k < 8; ++k) {
    const int tr = 7 - k;
    StepArgs f = mk(featImg + (size_t)k * 8 * 4 * IMG, 4,
                    hf0i + (size_t)k * SLOTI, 2, nullptr, 0,
                    0, c0f, hf0i + (size_t)(k + 1) * SLOTI, nullptr);
    StepArgs r = mk(featImg + (size_t)tr * 8 * 4 * IMG, 4,
                    hr0i + (size_t)(tr + 1) * SLOTI, 2, nullptr, 0,
                    1, c0r, hr0i + (size_t)tr * SLOTI, nullptr);
    conv_lstm_step<2><<<dim3(256, 1, 2), 256, 0, stream>>>(f, r);
  }

  // Layer 1 reverse: single step at t=7 (zero initial state -> skip h-prev group)
  {
    StepArgs s = mk(hf0i + (size_t)8 * SLOTI, 2, hr0i + (size_t)7 * SLOTI, 2,
                    nullptr, 0, 3, c1r, nullptr, h1r8);
    conv_lstm_step<1><<<dim3(512, 1, 1), 256, 0, stream>>>(s, s);
  }
  // Layer 1 forward chain: 8 singles, h-image ping-pong (read t&1, write (t+1)&1)
  for (int t = 0; t < 8; ++t) {
    uint16_t* himg = (t < 7) ? h1fi + (size_t)((t + 1) & 1) * SLOTI : nullptr;
    float* hf32 = (t == 7) ? h1f8 : nullptr;
    StepArgs s = mk(hf0i + (size_t)(t + 1) * SLOTI, 2, hr0i + (size_t)t * SLOTI, 2,
                    h1fi + (size_t)(t & 1) * SLOTI, 2, 2, c1f, himg, hf32);
    conv_lstm_step<1><<<dim3(512, 1, 1), 256, 0, stream>>>(s, s);
  }

  final_conv<<<dim3(32, 4), 256, 0, stream>>>(
      h1f8, h1r8, (const float*)d_in[17], (const float*)d_in[18], (float*)d_out);
}

// Round 5
// 745.796 us; speedup vs baseline: 4.6588x; 1.3304x over previous
//
#include <hip/hip_runtime.h>
#include <math.h>
#include <stdint.h>

// ConvLSTM (Seq2VecRNN2D) round 5: M-tile 128 (4-row bands, 512 thr), W triple-buffer
// + A double-buffer staged via global_load_lds, raw s_waitcnt vmcnt(N)+s_barrier
// pipeline (no vmcnt(0) drain per tap). 3-term bf16-split MFMA, fused LSTM cell.
// B=8 T=8 CIN=128 HID=64 G=256 H=W=32.
//
// Activation image per (slot,b,cg32): [34 y'][34 px][8 blk of 16B], blk = pl*4+kg
// stored at blk^(px&7); ch = cg*32+kg*8+j, pl0=hi bf16, pl1=lo bf16. Borders zero.
// Weight image per (combo,cg,tap,nt): [pl][4 g][16 hcp][8 b8 of 16B], b8 = kg+4*(hc&1)
// stored at b8^(hcp&7); hcp = hc_local>>1.
//
// DMA schedule (per wave, per barrier interval): 2 W chunks always; +4 A chunks at
// tap==0. vmcnt before barrier of tap t = issues after W[t]'s stage:
//   tap0: 2   tap1: 6   tap2: 6   tap>=3: 2.   (in-order vmcnt retirement, m135)

typedef __attribute__((ext_vector_type(8))) short short8;
typedef __attribute__((ext_vector_type(4))) float float4v;

namespace {
constexpr int IMG = 34 * 34 * 64;            // u16 per (slot,b,cg) image
constexpr size_t SLOTI = 16ull * IMG;        // u16 per h slot (8 b x 2 cg)
constexpr int ROWB = 34 * 128;               // bytes per image row (4352)
constexpr int PADB = 8192;                   // tail slack for DMA overshoot
}
template <int N> struct IC { static constexpr int v = N; };

__device__ __forceinline__ uint16_t bf16_rne(float x) {
  uint32_t u = __builtin_bit_cast(uint32_t, x);
  return (uint16_t)((u + 0x7FFFu + ((u >> 16) & 1u)) >> 16);
}
__device__ __forceinline__ float bf16_to_f(uint16_t h) {
  uint32_t u = ((uint32_t)h) << 16;
  return __builtin_bit_cast(float, u);
}

__device__ __forceinline__ void gl_lds16(const void* g, void* l) {
  __builtin_amdgcn_global_load_lds(
      (const __attribute__((address_space(1))) void*)g,
      (__attribute__((address_space(3))) void*)l, 16, 0, 0);
}

// ---- feature pack: fp32 [B][T][128][32][32] -> swizzled images [t][b][4cg] ----
__global__ void pack_features(const float* __restrict__ f, uint16_t* __restrict__ out) {
  const size_t i = (size_t)blockIdx.x * 256 + threadIdx.x;  // 16B-block index, < 2367488
  const int blk_s = (int)(i & 7);
  size_t pp = i >> 3;
  const int px = (int)(pp % 34); pp /= 34;
  const int yy = (int)(pp % 34); pp /= 34;
  const int cg = (int)(pp & 3);
  const int bt = (int)(pp >> 2);
  const int b = bt & 7, t = bt >> 3;
  const int blk = blk_s ^ (px & 7);
  const int pl = blk >> 2, kg = blk & 3;
  short8 sv;
  if (px == 0 || px == 33 || yy == 0 || yy == 33) {
    #pragma unroll
    for (int j = 0; j < 8; ++j) sv[j] = 0;
  } else {
    const int x = px - 1, y = yy - 1;
    #pragma unroll
    for (int j = 0; j < 8; ++j) {
      const int ch = cg * 32 + kg * 8 + j;
      const float fv = f[(((size_t)b * 8 + t) * 128 + ch) * 1024 + y * 32 + x];
      const uint16_t hi = bf16_rne(fv);
      sv[j] = (short)(pl ? bf16_rne(fv - bf16_to_f(hi)) : hi);
    }
  }
  *(short8*)(out + i * 8) = sv;
}

// ---- weight pack into swizzled images: per combo [cg][tap][nt][4096 u32] ----
struct WPackArgs {
  const float* wih[4]; const float* whh[4];
  const float* bih[4]; const float* bhh[4];
  uint32_t* wp; float* bp;
};
__global__ void pack_weights(WPackArgs A) {
  const int combo = blockIdx.y;
  const int idx = blockIdx.x * 256 + threadIdx.x;  // < 442368
  const int q = idx & 4095;
  const int rest = idx >> 12;
  const int nt = rest & 1;
  const int ct = rest >> 1;          // cg*9+tap
  const int tap = ct % 9, cg = ct / 9;
  const int w2 = q & 3;
  const int b8s = (q >> 2) & 7;
  const int hcp = (q >> 5) & 15;
  const int g = (q >> 9) & 3;
  const int pl = (q >> 11) & 1;
  const int b8 = b8s ^ (hcp & 7);
  const int kg = b8 & 3;
  const int hcl = hcp * 2 + (b8 >> 2);
  const int n = g * 64 + nt * 32 + hcl;
  const float* wih = A.wih[combo];
  const float* whh = A.whh[combo];
  uint32_t out = 0;
  #pragma unroll
  for (int e = 0; e < 2; ++e) {
    const int ch = cg * 32 + kg * 8 + w2 * 2 + e;
    const float wv = (ch < 128) ? wih[((size_t)n * 128 + ch) * 9 + tap]
                                : whh[((size_t)n * 64 + (ch - 128)) * 9 + tap];
    const uint16_t hi = bf16_rne(wv);
    const uint16_t v = pl ? bf16_rne(wv - bf16_to_f(hi)) : hi;
    out |= ((uint32_t)v) << (16 * e);
  }
  A.wp[(size_t)combo * 442368 + idx] = out;
  if (idx < 256) A.bp[combo * 256 + idx] = A.bih[combo][idx] + A.bhh[combo][idx];
}

struct StepArgs {
  const uint16_t* in0; const uint16_t* in1; const uint16_t* in2;  // images
  int nc0, nc1, nc2;         // cg counts per tensor
  const uint32_t* W;         // combo base: [cg][tap][nt][4096 u32]
  const float* bias;         // [256], n = gate*64+hc
  float* cbuf;               // plain fp32 [b][64][1024]
  uint16_t* himg;            // nullable: [b][2 cg][IMG]
  float* hf32;               // nullable: plain [b][64][1024]
};

// Block: b = bx>>4, 4-row band (bx>>1)&7, nt = bx&1. 512 threads = 8 waves;
// wave w: row r = w&3, hc-subgroup hcg = w>>2. Per wave: 2 x-halves x 4 gates.
__global__ __launch_bounds__(512, 2) void conv_lstm_step(StepArgs A0, StepArgs A1) {
  extern __shared__ char smem[];
  char* Asm_ = smem;               // 2 x 32768 (A double-buffer; 26112 used each)
  char* Wsm_ = smem + 65536;       // 3 x 16384 (W triple-buffer)

  const StepArgs a = (blockIdx.z == 0) ? A0 : A1;
  const int bx = blockIdx.x;
  const int nt = bx & 1;
  const int band = (bx >> 1) & 7;
  const int b = bx >> 4;
  const int y0 = band * 4;
  const int tid = threadIdx.x;
  const int lane = tid & 63;
  const int w = tid >> 6;
  const int m15 = lane & 15;
  const int kg = lane >> 4;
  const int r = w & 3;
  const int hcg = w >> 2;

  // fragment read offsets (bytes), conflict-free via baked swizzle
  int offA[2][3][2];
  #pragma unroll
  for (int xh = 0; xh < 2; ++xh)
    #pragma unroll
    for (int kx = 0; kx < 3; ++kx)
      #pragma unroll
      for (int pl = 0; pl < 2; ++pl) {
        const int px = xh * 16 + kx + m15;
        const int sw = (pl * 4 + kg) ^ (px & 7);
        offA[xh][kx][pl] = r * ROWB + px * 128 + sw * 16;
      }
  int offW[2][4];
  {
    const int hcp = hcg * 8 + (m15 >> 1);
    const int b8 = kg + 4 * (m15 & 1);
    #pragma unroll
    for (int pl = 0; pl < 2; ++pl)
      #pragma unroll
      for (int g = 0; g < 4; ++g)
        offW[pl][g] = (((pl * 4 + g) * 16 + hcp) * 8 + (b8 ^ (hcp & 7))) * 16;
  }

  const int ncg = a.nc0 + a.nc1 + a.nc2;
  auto abase = [&](int cg) -> const char* {
    const uint16_t* t;
    if (cg < a.nc0) t = a.in0 + ((size_t)b * a.nc0 + cg) * IMG;
    else if (cg < a.nc0 + a.nc1) t = a.in1 + ((size_t)b * a.nc1 + (cg - a.nc0)) * IMG;
    else t = a.in2 + ((size_t)b * a.nc2 + (cg - a.nc0 - a.nc1)) * IMG;
    return (const char*)t + (size_t)y0 * ROWB;
  };
  // 4 chunks/wave (32 KB; 26112 used, tail lands in dead LDS; source has PADB slack)
  auto stageA = [&](int cgi, int par) {
    const char* g = abase(cgi);
    char* d = Asm_ + par * 32768;
    #pragma unroll
    for (int j = 0; j < 4; ++j)
      gl_lds16(g + (size_t)(4 * w + j) * 1024 + lane * 16, d + (4 * w + j) * 1024);
  };
  // 2 chunks/wave (16 KB tile)
  auto stageW = [&](int cgs, int taps, int slot) {
    const char* g = (const char*)a.W + ((size_t)((cgs * 9 + taps) * 2 + nt) << 14);
    char* d = Wsm_ + slot * 16384;
    #pragma unroll
    for (int j = 0; j < 2; ++j)
      gl_lds16(g + (size_t)(2 * w + j) * 1024 + lane * 16, d + (2 * w + j) * 1024);
  };

  float4v acc[2][4];
  #pragma unroll
  for (int xh = 0; xh < 2; ++xh)
    #pragma unroll
    for (int g = 0; g < 4; ++g) acc[xh][g] = (float4v){0.f, 0.f, 0.f, 0.f};

  // Prologue: A[0] then W[0,0], W[0,1] (order matters for vmcnt math).
  stageA(0, 0);
  stageW(0, 0, 0);
  stageW(0, 1, 1);

  for (int cg = 0; cg < ncg; ++cg) {
    auto tap_body = [&](auto tapc) {
      constexpr int TAP = decltype(tapc)::v;
      constexpr int CNT = (TAP == 1 || TAP == 2) ? 6 : 2;
      asm volatile("s_waitcnt vmcnt(%0)\n\ts_barrier" :: "n"(CNT) : "memory");
      const int lin = cg * 9 + TAP;
      {  // stage W for lin+2 (wrap to a dead-but-valid tile near the end)
        const int l2 = lin + 2;
        int cgs = l2 / 9;
        const int taps = l2 % 9;
        if (cgs >= ncg) cgs = 0;
        stageW(cgs, taps, l2 % 3);
      }
      if (TAP == 0) {  // stage next cg's A into the other parity
        const int nx = (cg + 1 < ncg) ? cg + 1 : 0;
        stageA(nx, (cg + 1) & 1);
      }
      constexpr int ky = TAP / 3, kx = TAP % 3;
      const char* Ab = Asm_ + (cg & 1) * 32768 + ky * ROWB;
      const char* Wb = Wsm_ + (lin % 3) * 16384;
      short8 af[2][2];
      #pragma unroll
      for (int xh = 0; xh < 2; ++xh)
        #pragma unroll
        for (int pl = 0; pl < 2; ++pl)
          af[xh][pl] = *(const short8*)(Ab + offA[xh][kx][pl]);
      short8 wfr[2][4];
      #pragma unroll
      for (int pl = 0; pl < 2; ++pl)
        #pragma unroll
        for (int g = 0; g < 4; ++g)
          wfr[pl][g] = *(const short8*)(Wb + offW[pl][g]);
      #pragma unroll
      for (int xh = 0; xh < 2; ++xh)
        #pragma unroll
        for (int g = 0; g < 4; ++g) {
          acc[xh][g] = __builtin_amdgcn_mfma_f32_16x16x32_bf16(af[xh][0], wfr[0][g], acc[xh][g], 0, 0, 0);
          acc[xh][g] = __builtin_amdgcn_mfma_f32_16x16x32_bf16(af[xh][0], wfr[1][g], acc[xh][g], 0, 0, 0);
          acc[xh][g] = __builtin_amdgcn_mfma_f32_16x16x32_bf16(af[xh][1], wfr[0][g], acc[xh][g], 0, 0, 0);
        }
    };
    tap_body(IC<0>{}); tap_body(IC<1>{}); tap_body(IC<2>{});
    tap_body(IC<3>{}); tap_body(IC<4>{}); tap_body(IC<5>{});
    tap_body(IC<6>{}); tap_body(IC<7>{}); tap_body(IC<8>{});
  }
  asm volatile("s_waitcnt vmcnt(0)" ::: "memory");  // drain dummy restages

  // ---- fused LSTM cell epilogue ----
  const int hcl = hcg * 16 + m15;
  const int hc = nt * 32 + hcl;
  const int y = y0 + r;
  float bi[4];
  #pragma unroll
  for (int g = 0; g < 4; ++g) bi[g] = a.bias[g * 64 + hc];
  float* crow = a.cbuf + ((size_t)(b * 64 + hc)) * 1024 + y * 32;
  float* hrow = a.hf32 ? a.hf32 + ((size_t)(b * 64 + hc)) * 1024 + y * 32 : nullptr;
  uint16_t* hb = a.himg ? a.himg + ((size_t)(b * 2 + nt)) * IMG : nullptr;
  const int kgb = hcl >> 3, jj = hcl & 7;
  #pragma unroll
  for (int xh = 0; xh < 2; ++xh) {
    const int x0 = xh * 16 + kg * 4;
    float4v cv = *(float4v*)(crow + x0);
    float4v cn, hn;
    #pragma unroll
    for (int q = 0; q < 4; ++q) {
      const float ig = 1.f / (1.f + expf(-(acc[xh][0][q] + bi[0])));
      const float fg = 1.f / (1.f + expf(-(acc[xh][1][q] + bi[1])));
      const float gg = tanhf(acc[xh][2][q] + bi[2]);
      const float og = 1.f / (1.f + expf(-(acc[xh][3][q] + bi[3])));
      const float c2 = fg * cv[q] + ig * gg;
      cn[q] = c2;
      hn[q] = og * tanhf(c2);
    }
    *(float4v*)(crow + x0) = cn;
    if (hrow) *(float4v*)(hrow + x0) = hn;
    if (hb) {
      #pragma unroll
      for (int q = 0; q < 4; ++q) {
        const int px = x0 + q + 1;
        const int sw = px & 7;
        const uint16_t hi = bf16_rne(hn[q]);
        const uint16_t lo = bf16_rne(hn[q] - bf16_to_f(hi));
        const size_t p16 = ((size_t)(y + 1) * 34 + px) * 64;
        hb[p16 + (size_t)(kgb ^ sw) * 8 + jj] = hi;
        hb[p16 + (size_t)((4 + kgb) ^ sw) * 8 + jj] = lo;
      }
    }
  }
  if (hb) {   // keep image borders zero (ws is re-poisoned every call)
    {
      const int rr = tid >> 7;             // 0..3
      const int hlf = (tid >> 6) & 1;
      const int jx = tid & 63;
      hb[((size_t)(y0 + 1 + rr) * 34 + hlf * 33) * 64 + jx] = 0;
    }
    if (band == 0) for (int i = tid; i < 2176; i += 512) hb[i] = 0;
    if (band == 7) for (int i = tid; i < 2176; i += 512) hb[(size_t)33 * 2176 + i] = 0;
  }
}

// out[b][o][p] = relu(b_out[o] + sum_c w_out[o][c] * last[b][c][p])  (fp32 inputs)
__global__ void final_conv(const float* __restrict__ h1f_last, const float* __restrict__ h1r_last,
                           const float* __restrict__ wout, const float* __restrict__ bout,
                           float* __restrict__ out) {
  __shared__ float Ws[16 * 128];
  const int oq = blockIdx.y;
  for (int i = threadIdx.x; i < 16 * 128; i += 256) Ws[i] = wout[oq * 16 * 128 + i];
  __syncthreads();
  const int gp = blockIdx.x * 256 + threadIdx.x;
  const int b = gp >> 10, p = gp & 1023;
  float acc[16];
  #pragma unroll
  for (int o = 0; o < 16; ++o) acc[o] = bout[oq * 16 + o];
  for (int c = 0; c < 128; ++c) {
    const float xv = (c < 64) ? h1f_last[((size_t)b * 64 + c) * 1024 + p]
                              : h1r_last[((size_t)b * 64 + (c - 64)) * 1024 + p];
    #pragma unroll
    for (int o = 0; o < 16; ++o) acc[o] = fmaf(xv, Ws[o * 128 + c], acc[o]);
  }
  #pragma unroll
  for (int o = 0; o < 16; ++o) {
    const float v = acc[o];
    out[((size_t)b * 64 + oq * 16 + o) * 1024 + p] = v > 0.f ? v : 0.f;
  }
}

extern "C" void kernel_launch(void* const* d_in, const int* in_sizes, int n_in,
                              void* d_out, int out_size, void* d_ws, size_t ws_size,
                              hipStream_t stream) {
  char* p = (char*)d_ws;
  uint16_t* featImg = (uint16_t*)p; p += (size_t)8 * 8 * 4 * IMG * 2 + PADB;  // 37.9 MB
  uint32_t* WP = (uint32_t*)p;      p += (size_t)4 * 442368 * 4;              // 7.1 MB
  float* bp = (float*)p;            p += 4096;
  uint16_t* hf0i = (uint16_t*)p;    p += (size_t)9 * SLOTI * 2 + PADB;        // 21.3 MB
  uint16_t* hr0i = (uint16_t*)p;    p += (size_t)9 * SLOTI * 2 + PADB;        // 21.3 MB
  uint16_t* h1fi = (uint16_t*)p;    p += (size_t)2 * SLOTI * 2 + PADB;        // 4.7 MB
  float* c0f = (float*)p;           p += (size_t)4 * 2097152;                 // c states
  float* c0r = c0f + 524288;
  float* c1f = c0r + 524288;
  float* c1r = c1f + 524288;
  float* h1f8 = (float*)p;          p += 2097152;
  float* h1r8 = (float*)p;          p += 2097152;

  hipMemsetAsync(c0f, 0, (size_t)4 * 2097152, stream);
  hipMemsetAsync(hf0i, 0, (size_t)SLOTI * 2, stream);                     // hf0 slot 0
  hipMemsetAsync(hr0i + (size_t)8 * SLOTI, 0, (size_t)SLOTI * 2, stream); // hr0 slot 8
  hipMemsetAsync(h1fi, 0, (size_t)SLOTI * 2, stream);                     // h1f parity-0 slot

  pack_features<<<dim3(9248), 256, 0, stream>>>((const float*)d_in[0], featImg);

  WPackArgs wa;
  for (int combo = 0; combo < 4; ++combo) {
    const int base = 1 + combo * 4;
    wa.wih[combo] = (const float*)d_in[base];
    wa.whh[combo] = (const float*)d_in[base + 1];
    wa.bih[combo] = (const float*)d_in[base + 2];
    wa.bhh[combo] = (const float*)d_in[base + 3];
  }
  wa.wp = WP; wa.bp = bp;
  pack_weights<<<dim3(1728, 4), 256, 0, stream>>>(wa);

  constexpr int DYN_LDS = 114688;   // 2x32KB A + 3x16KB W
  (void)hipFuncSetAttribute((const void*)conv_lstm_step,
                            hipFuncAttributeMaxDynamicSharedMemorySize, DYN_LDS);

  auto mk = [&](const uint16_t* i0, int n0, const uint16_t* i1, int n1,
                const uint16_t* i2, int n2, int combo, float* cb,
                uint16_t* himg, float* hf32) {
    StepArgs s;
    s.in0 = i0; s.in1 = i1; s.in2 = i2;
    s.nc0 = n0; s.nc1 = n1; s.nc2 = n2;
    s.W = WP + (size_t)combo * 442368; s.bias = bp + combo * 256;
    s.cbuf = cb; s.himg = himg; s.hf32 = hf32;
    return s;
  };

  // Layer 0: 8 pair launches (fwd step k, rev step 7-k); 128 blocks/dir, 512 thr.
  for (int k = 0; k < 8; ++k) {
    const int tr = 7 - k;
    StepArgs f = mk(featImg + (size_t)k * 8 * 4 * IMG, 4,
                    hf0i + (size_t)k * SLOTI, 2, nullptr, 0,
                    0, c0f, hf0i + (size_t)(k + 1) * SLOTI, nullptr);
    StepArgs r = mk(featImg + (size_t)tr * 8 * 4 * IMG, 4,
                    hr0i + (size_t)(tr + 1) * SLOTI, 2, nullptr, 0,
                    1, c0r, hr0i + (size_t)tr * SLOTI, nullptr);
    conv_lstm_step<<<dim3(128, 1, 2), 512, DYN_LDS, stream>>>(f, r);
  }

  // Layer 1: fwd t=0 pairs with the single reverse step (t=7, zero init state).
  for (int t = 0; t < 8; ++t) {
    uint16_t* himg = (t < 7) ? h1fi + (size_t)((t + 1) & 1) * SLOTI : nullptr;
    float* hf32 = (t == 7) ? h1f8 : nullptr;
    StepArgs s = mk(hf0i + (size_t)(t + 1) * SLOTI, 2, hr0i + (size_t)t * SLOTI, 2,
                    h1fi + (size_t)(t & 1) * SLOTI, 2, 2, c1f, himg, hf32);
    if (t == 0) {
      StepArgs rv = mk(hf0i + (size_t)8 * SLOTI, 2, hr0i + (size_t)7 * SLOTI, 2,
                       nullptr, 0, 3, c1r, nullptr, h1r8);
      conv_lstm_step<<<dim3(128, 1, 2), 512, DYN_LDS, stream>>>(s, rv);
    } else {
      conv_lstm_step<<<dim3(128, 1, 1), 512, DYN_LDS, stream>>>(s, s);
    }
  }

  final_conv<<<dim3(32, 4), 256, 0, stream>>>(
      h1f8, h1r8, (const float*)d_in[17], (const float*)d_in[18], (float*)d_out);
}